// Round 4
// baseline (356.562 us; speedup 1.0000x reference)
//
#include <hip/hip_runtime.h>

// CapsNet dynamic routing — fp32 in / fp32 out.
// R0/R2/R3 post-mortem: warm MODE0 = 66.3/66.0/66.1 us across THREE different
// W-staging schedules (sync LDS, async DMA dbuf, direct global) -> the wall is
// schedule-invariant: W re-delivered 8x into L2 (301 MB/pass), 3 waves/SIMD,
// lockstep stage collisions. R4 attacks the invariant: 1024-thread blocks,
// 1 block/CU (grid 128x2 = 256 exact), 4 g-groups x 8 b = 32 b per block ->
// W[i] staged ONCE per block, reused 32x (L2 W traffic /4 = 75 MB/pass),
// 4 waves/SIMD, and VGPR cap 512/wave at 1 block/CU so the register-prefetch
// pipeline (R1 idea that spilled at cap 170) now fits: tmp0/tmp1 issued after
// barrier A, in flight across the whole compute phase; mid-loop barriers are
// raw s_barrier + lgkmcnt only (no vmcnt drain). Staging coalesced (TA-light,
// high MLP -> no cold-HBM penalty, unlike R3's per-lane lines).
// B=64, Ni=1152, Di=8, No=64, Do=16.
// u[b,i,o,d] = sum_k W[i*8192 + (o*16+d)*8 + k] * x[b*9216 + i*8 + k]
// it0: c=1/64       -> s0 -> v0
// it1: l=<u,v0>     -> c1 -> s1 -> v1
// it2: l=<u,v0+v1>  -> c2 (OUT [B,Ni,No]) -> s2 -> v2 (OUT [B,No,Do])

#define B_      64
#define NI_     1152
#define DI_     8
#define NO_     64
#define DO_     16
#define NOD_    1024
#define CH_     128
#define CI_     9
#define BGT_    8       // b's per thread (per g-group)
#define NG_     4       // g-groups per block
#define BGB_    32      // b's per block = BGT_*NG_
#define BSPLIT_ 2
#define V_ELEMS 65536
#define PADR    33      // float4 slots per o-row in LDS tile (132 floats)

static_assert(CH_ * CI_ == NI_, "chunking");
static_assert(BGB_ * BSPLIT_ == B_, "b split");

#define RAW_BARRIER() do { \
    asm volatile("s_waitcnt lgkmcnt(0)" ::: "memory"); \
    __builtin_amdgcn_s_barrier(); \
    __builtin_amdgcn_sched_barrier(0); } while (0)

// MODE 0: c=1/64 (applied in squash), acc sum_i u       -> part
// MODE 1: l=<u,v0>, softmax over o, acc c*u             -> part
// MODE 2: l=<u,v0+v1>, softmax, write c (fp32), acc c*u -> part
template <int MODE>
__global__ __launch_bounds__(1024, 4)
void caps_pass(const float* __restrict__ X,
               const float* __restrict__ W,
               const float* __restrict__ vin,
               float* __restrict__ part,
               float* __restrict__ rw)
{
    __shared__ float4 wtile[NO_ * PADR];          // 33.8 KB padded W[i] tile
    __shared__ float  x_lds[BGB_][CI_ * DI_];     // 9.2 KB
    __shared__ float  e_lds[2][BGB_][NO_];        // 16 KB (parity dbuf)
    __shared__ float  invS[2][BGB_];

    const int t  = threadIdx.x;
    const int o  = (t >> 2) & 63, q = t & 3, g = t >> 8;
    const int ch = blockIdx.x;                 // siblings 128 apart -> same XCD
    const int bg0 = blockIdx.y * BGB_;
    const int i0 = ch * CI_;

    const float4* Wq = (const float4*)W;

    // ---- prologue: prefetch W[i0] (2 coalesced dwordx4/thread, whole tile) ----
    float4 tmp0, tmp1;
    {
        const float4* wg = Wq + (size_t)i0 * 2048;
        tmp0 = wg[t]; tmp1 = wg[t + 1024];
    }

    // stage x[bg0..bg0+31][i0..i0+8][0..7]: 576 float4, coalesced
    if (t < BGB_ * CI_ * DI_ / 4) {
        const int bb = t / (CI_ * DI_ / 4), r = t - bb * (CI_ * DI_ / 4);
        ((float4*)x_lds)[t] =
            ((const float4*)(X + ((size_t)(bg0 + bb) * NI_ + i0) * DI_))[r];
    }

    // routing vector -> registers: v[b][o*16 + q*4 + j]  (coalesced per group)
    float vreg[BGT_][4];
    if (MODE >= 1) {
#pragma unroll
        for (int b = 0; b < BGT_; ++b) {
            float4 qv = *((const float4*)(vin + (size_t)(bg0 + g * BGT_ + b) * NOD_
                                          + 4 * (t & 255)));
            vreg[b][0]=qv.x; vreg[b][1]=qv.y; vreg[b][2]=qv.z; vreg[b][3]=qv.w;
        }
    }

    float acc[BGT_][4];
#pragma unroll
    for (int b = 0; b < BGT_; ++b) { acc[b][0]=0.f; acc[b][1]=0.f; acc[b][2]=0.f; acc[b][3]=0.f; }

    RAW_BARRIER();   // x_lds ready (tmp0/tmp1 stay in flight — no vmcnt drain)

    for (int ci = 0; ci < CI_; ++ci) {
        const int i   = i0 + ci;
        const int par = ci & 1;

        // ---- write prefetched W[i] to padded tile (vmcnt wait lands here;
        //      loads were issued a full iteration ago -> mostly complete) ----
        wtile[(t >> 5) * PADR + (t & 31)] = tmp0;
        {
            const int f = t + 1024;
            wtile[(f >> 5) * PADR + (f & 31)] = tmp1;
        }
        RAW_BARRIER();   // A: tile ready (also fences prev-ci tile reads)

        // ---- issue prefetch of W[i+1]; in flight across the whole compute ----
        if (ci + 1 < CI_) {
            const float4* wg = Wq + (size_t)(i + 1) * 2048;
            tmp0 = wg[t]; tmp1 = wg[t + 1024];
        }

        // ---- wf = W[i][o][4q+jj][0..7] via 8 b128 reads from padded tile ----
        float wf[4][8];
#pragma unroll
        for (int jj = 0; jj < 4; ++jj) {
            float4 a0 = wtile[o * PADR + 8 * q + 2 * jj];
            float4 a1 = wtile[o * PADR + 8 * q + 2 * jj + 1];
            wf[jj][0]=a0.x; wf[jj][1]=a0.y; wf[jj][2]=a0.z; wf[jj][3]=a0.w;
            wf[jj][4]=a1.x; wf[jj][5]=a1.y; wf[jj][6]=a1.z; wf[jj][7]=a1.w;
        }

        float u[BGT_][4];
#pragma unroll
        for (int b = 0; b < BGT_; ++b) {
            const float* xb = &x_lds[g * BGT_ + b][ci * DI_];   // broadcast reads
            const float x0=xb[0],x1=xb[1],x2=xb[2],x3=xb[3];
            const float x4=xb[4],x5=xb[5],x6=xb[6],x7=xb[7];
#pragma unroll
            for (int jj = 0; jj < 4; ++jj) {
                float s = wf[jj][0] * x0;
                s = fmaf(wf[jj][1], x1, s); s = fmaf(wf[jj][2], x2, s);
                s = fmaf(wf[jj][3], x3, s); s = fmaf(wf[jj][4], x4, s);
                s = fmaf(wf[jj][5], x5, s); s = fmaf(wf[jj][6], x6, s);
                s = fmaf(wf[jj][7], x7, s);
                u[b][jj] = s;
            }
            if (MODE >= 1) {
                float a = u[b][0]*vreg[b][0] + u[b][1]*vreg[b][1]
                        + u[b][2]*vreg[b][2] + u[b][3]*vreg[b][3];
                a += __shfl_xor(a, 1);
                a += __shfl_xor(a, 2);          // full 16-d dot within quad
                if (q == 0) e_lds[par][g * BGT_ + b][o] = __expf(a);
            } else {
                acc[b][0]+=u[b][0]; acc[b][1]+=u[b][1];
                acc[b][2]+=u[b][2]; acc[b][3]+=u[b][3];
            }
        }

        if (MODE >= 1) {
            RAW_BARRIER();   // B: e_lds[par] complete (tile reads also done)
            {
                const int bb = t >> 5, l = t & 31;     // 32 half-waves x 32 lanes
                float s = e_lds[par][bb][l] + e_lds[par][bb][l + 32];
                s += __shfl_xor(s, 1);  s += __shfl_xor(s, 2);  s += __shfl_xor(s, 4);
                s += __shfl_xor(s, 8);  s += __shfl_xor(s, 16);
                if (l == 0) invS[par][bb] = 1.0f / s;
            }
            RAW_BARRIER();   // C: invS ready
#pragma unroll
            for (int b = 0; b < BGT_; ++b) {
                const float c = e_lds[par][g * BGT_ + b][o] * invS[par][g * BGT_ + b];
                acc[b][0] = fmaf(c, u[b][0], acc[b][0]);
                acc[b][1] = fmaf(c, u[b][1], acc[b][1]);
                acc[b][2] = fmaf(c, u[b][2], acc[b][2]);
                acc[b][3] = fmaf(c, u[b][3], acc[b][3]);
                if (MODE == 2 && q == 0)
                    rw[((size_t)(bg0 + g * BGT_ + b) * NI_ + i) * NO_ + o] = c;
            }
            // no extra WAR barrier: next ci writes e_lds[par^1]; tile rewrite
            // is fenced by barriers B/C which follow all tile reads.
        } else {
            RAW_BARRIER();   // MODE 0: fence tile reads before next overwrite
        }
    }

    // partial s: part[b][ch][...] (coalesced float4 per g-group)
#pragma unroll
    for (int b = 0; b < BGT_; ++b) {
        float4 val;
        val.x=acc[b][0]; val.y=acc[b][1]; val.z=acc[b][2]; val.w=acc[b][3];
        *((float4*)(part + (((size_t)(bg0 + g * BGT_ + b) * CH_ + ch) * NOD_
                            + 4 * (t & 255)))) = val;
    }
}

// Reduce partials over CH_ chunks (float4), squash over d, emit v.
// MODE 0: s*=1/64 -> v0 | MODE 1: w01 = v0 + squash(s1) | MODE 2: v2 -> d_out
template <int MODE>
__global__ __launch_bounds__(128)
void caps_squash(const float* __restrict__ part, const float* __restrict__ v0in,
                 float* __restrict__ vout)
{
    const int c4 = blockIdx.x * 128 + threadIdx.x;    // 0..16383: b*256 + o*4 + dq
    const int b = c4 >> 8, od4 = c4 & 255;
    const float4* p = (const float4*)part + (size_t)b * CH_ * 256 + od4;
    float4 s = {0.f, 0.f, 0.f, 0.f};
#pragma unroll 8
    for (int ch = 0; ch < CH_; ++ch) {
        float4 q = p[(size_t)ch * 256];
        s.x += q.x; s.y += q.y; s.z += q.z; s.w += q.w;
    }
    if (MODE == 0) { s.x*=(1.f/64.f); s.y*=(1.f/64.f); s.z*=(1.f/64.f); s.w*=(1.f/64.f); }
    float s2 = s.x*s.x + s.y*s.y + s.z*s.z + s.w*s.w;
    s2 += __shfl_xor(s2, 1); s2 += __shfl_xor(s2, 2);   // 4 dq-lanes = 16 d
    const float scale = s2 / ((1.0f + s2) * sqrtf(s2 + 1e-7f));
    float4 v; v.x = scale*s.x; v.y = scale*s.y; v.z = scale*s.z; v.w = scale*s.w;
    if (MODE == 1) {
        float4 v0 = ((const float4*)v0in)[c4];
        v.x += v0.x; v.y += v0.y; v.z += v0.z; v.w += v0.w;
    }
    ((float4*)vout)[c4] = v;
}

// Safety fallback (R11's passing kernel) — only if ws is unexpectedly tiny.
__global__ __launch_bounds__(1024, 1)
void caps_naive(const float* __restrict__ X, const float* __restrict__ W,
                float* __restrict__ outv, float* __restrict__ outc)
{
    __shared__ float xs[NI_ * DI_];
    __shared__ float agree[NO_];
    __shared__ float expo[NO_];
    __shared__ float s2sh[NO_];
    __shared__ float den;

    const int b = blockIdx.x, tid = threadIdx.x;
    const int o = tid >> 4, d = tid & 15;

    for (int f = tid; f < NI_ * DI_; f += 1024)
        xs[f] = X[(size_t)b * NI_ * DI_ + f];
    __syncthreads();

    float vprev = 0.f, v0 = 0.f, vout = 0.f;
    for (int phase = 0; phase < 3; ++phase) {
        float sacc = 0.f;
        for (int i = 0; i < NI_; ++i) {
            const float* wp = W + (size_t)i * 8192 + (size_t)tid * 8;
            const float* xp = xs + i * DI_;
            float u = 0.f;
#pragma unroll
            for (int k = 0; k < 8; ++k) u = fmaf(wp[k], xp[k], u);
            if (phase == 0) { sacc += u; continue; }
            if (d == 0) agree[o] = 0.f;
            __syncthreads();
            atomicAdd(&agree[o], u * vprev);
            __syncthreads();
            if (tid == 0) den = 0.f;
            __syncthreads();
            if (d == 0) { float e = __expf(agree[o]); expo[o] = e; atomicAdd(&den, e); }
            __syncthreads();
            float c = expo[o] / den;
            sacc = fmaf(c, u, sacc);
            if (phase == 2 && d == 0)
                outc[((size_t)b * NI_ + i) * NO_ + o] = c;
            __syncthreads();
        }
        if (phase == 0) sacc *= (1.0f / 64.0f);
        if (d == 0) s2sh[o] = 0.f;
        __syncthreads();
        atomicAdd(&s2sh[o], sacc * sacc);
        __syncthreads();
        const float s2 = s2sh[o];
        const float scale = s2 / ((1.0f + s2) * sqrtf(s2 + 1e-7f));
        const float vv = scale * sacc;
        if (phase == 0)      { v0 = vv; vprev = vv; }
        else if (phase == 1) { vprev = v0 + vv; }
        else                 { vout = vv; }
        __syncthreads();
    }
    outv[(size_t)b * (NO_ * DO_) + tid] = vout;
}

extern "C" void kernel_launch(void* const* d_in, const int* in_sizes, int n_in,
                              void* d_out, int out_size, void* d_ws, size_t ws_size,
                              hipStream_t stream)
{
    const float *X, *W;
    if (in_sizes[0] < in_sizes[1]) { X = (const float*)d_in[0]; W = (const float*)d_in[1]; }
    else                           { X = (const float*)d_in[1]; W = (const float*)d_in[0]; }

    float* out  = (float*)d_out;
    float* outv = out;             // v: [B,No,Do] fp32
    float* outc = out + V_ELEMS;   // c: [B,Ni,No] fp32

    const size_t needBig = ((size_t)B_ * CH_ * NOD_ + 2 * (size_t)B_ * NOD_) * sizeof(float);
    if (ws_size < needBig) {       // never expected (ws >= 64 MB measured R12)
        caps_naive<<<B_, 1024, 0, stream>>>(X, W, outv, outc);
        return;
    }

    float* part = (float*)d_ws;                      // 33.5 MB
    float* v0   = part + (size_t)B_ * CH_ * NOD_;
    float* w01  = v0 + (size_t)B_ * NOD_;

    dim3 gP(CH_, BSPLIT_), blk(1024), gS(128), blkS(128);
    caps_pass<0><<<gP, blk, 0, stream>>>(X, W, nullptr, part, nullptr);
    caps_squash<0><<<gS, blkS, 0, stream>>>(part, nullptr, v0);
    caps_pass<1><<<gP, blk, 0, stream>>>(X, W, v0, part, nullptr);
    caps_squash<1><<<gS, blkS, 0, stream>>>(part, v0, w01);
    caps_pass<2><<<gP, blk, 0, stream>>>(X, W, w01, part, outc);
    caps_squash<2><<<gS, blkS, 0, stream>>>(part, nullptr, outv);
}

// Round 5
// 235.975 us; speedup vs baseline: 1.5110x; 1.5110x over previous
//
#include <hip/hip_runtime.h>

// CapsNet dynamic routing — fp32 in / fp32 out.
// Evidence through R4: warm pass = 66.3/66.0/~74 us across sync-LDS (R0),
// async-DMA-dbuf (R2), direct-global (R3) W paths; register-prefetch spills
// whenever VGPR cap < ~170 (R1 at cap 168 w/ +32 prefetch, R4 at cap 128).
// R2~R0 rules out staging-latency; R3~R0 rules out W delivery path. Cycle
// model accounts for ~5K of 13.2K cy/ci/CU -> residual = phase-lockstep:
// co-resident blocks run identical ci phases simultaneously, saturating one
// pipe at a time (VMEM burst / LDS burst / VALU burst) with barrier-coupled
// convergence waste. R5 = R0 structure (proven best, VGPR-safe, 3 blk/CU) +
// (1) per-block ci phase ROTATION (ci iterations are independent in all
// modes: softmax is per-i, acc order-invariant, rw per-i) so same-CU blocks
// overlap different phases; (2) explicit float4 x_lds reads (ds_read_b128,
// cuts LDS-pipe issue up to 4x vs scalar b32).
// B=64, Ni=1152, Di=8, No=64, Do=16.
// u[b,i,o,d] = sum_k W[i*8192 + (o*16+d)*8 + k] * x[b*9216 + i*8 + k]
// it0: c=1/64       -> s0 -> v0
// it1: l=<u,v0>     -> c1 -> s1 -> v1
// it2: l=<u,v0+v1>  -> c2 (OUT [B,Ni,No]) -> s2 -> v2 (OUT [B,No,Do])

#define B_      64
#define NI_     1152
#define DI_     8
#define NO_     64
#define DO_     16
#define NOD_    1024
#define CH_     96
#define CI_     12
#define BG_     8
#define BSPLIT_ 8
#define V_ELEMS 65536
#define PADR    33      // float4 slots per o-row in LDS tile (132 floats)

static_assert(CH_ * CI_ == NI_, "chunking");
static_assert(BG_ * BSPLIT_ == B_, "b split");

// MODE 0: c=1/64 (applied in squash), acc sum_i u       -> part
// MODE 1: l=<u,v0>, softmax over o, acc c*u             -> part
// MODE 2: l=<u,v0+v1>, softmax, write c (fp32), acc c*u -> part
template <int MODE>
__global__ __launch_bounds__(256, 3)
void caps_pass(const float* __restrict__ X,
               const float* __restrict__ W,
               const float* __restrict__ vin,
               float* __restrict__ part,
               float* __restrict__ rw)
{
    __shared__ float  x_lds[BG_][CI_ * DI_];   // 3 KB
    __shared__ float4 wtile[NO_ * PADR];       // 33 KB padded W[i] tile
    __shared__ float  e_lds[BG_][NO_];         // 2 KB
    __shared__ float  invS[BG_];

    const int t  = threadIdx.x;
    const int o  = t >> 2, q = t & 3;
    const int ch = blockIdx.x;            // same-ch blocks 96 apart -> same XCD
    const int by = blockIdx.y;
    const int b0 = by * BG_;
    const int i0 = ch * CI_;

    // phase rotation: same-CU co-resident blocks start at different ci so
    // their VMEM/LDS/VALU phases interleave instead of colliding.
    const int phase = (ch + 3 * by) % CI_;

    // stage x[b0..b0+7][i0..i0+11][0..7]: 192 float4, coalesced
    for (int f = t; f < BG_ * CI_ * DI_ / 4; f += 256) {
        int bb = f / (CI_ * DI_ / 4), r = f - bb * (CI_ * DI_ / 4);
        ((float4*)x_lds)[f] =
            ((const float4*)(X + ((size_t)(b0 + bb) * NI_ + i0) * DI_))[r];
    }
    // routing vector -> registers: v[b][o*16 + q*4 + j]  (coalesced: addr = 4t)
    float vreg[BG_][4];
    if (MODE >= 1) {
#pragma unroll
        for (int b = 0; b < BG_; ++b) {
            float4 qv = *((const float4*)(vin + (size_t)(b0 + b) * NOD_ + 4 * t));
            vreg[b][0]=qv.x; vreg[b][1]=qv.y; vreg[b][2]=qv.z; vreg[b][3]=qv.w;
        }
    }
    __syncthreads();

    float acc[BG_][4];
#pragma unroll
    for (int b = 0; b < BG_; ++b) { acc[b][0]=0.f; acc[b][1]=0.f; acc[b][2]=0.f; acc[b][3]=0.f; }

    const float4* Wq = (const float4*)W;

    int ci = phase;
    for (int cc = 0; cc < CI_; ++cc) {
        const int i = i0 + ci;

        // ---- stage W[i] (2048 float4 = 32 KB): 8 coalesced dwordx4/thread ----
        // Overwrite safety: all tile reads of the previous iteration precede
        // that iteration's barrier B/C (or MODE-0 end barrier).
        const float4* wg = Wq + (size_t)i * 2048;
        float4 tmp[8];
#pragma unroll
        for (int j = 0; j < 8; ++j) tmp[j] = wg[t + 256 * j];
#pragma unroll
        for (int j = 0; j < 8; ++j) {
            const int f = t + 256 * j;                    // linear float4 idx
            wtile[(f >> 5) * PADR + (f & 31)] = tmp[j];   // padded row
        }
        __syncthreads();   // A: tile ready

        // ---- wf = W[i][o][4q+jj][0..7] via 8 b128 reads (bank-optimal) ----
        float wf[4][8];
#pragma unroll
        for (int jj = 0; jj < 4; ++jj) {
            float4 a0 = wtile[o * PADR + (4 * q + jj) * 2];
            float4 a1 = wtile[o * PADR + (4 * q + jj) * 2 + 1];
            wf[jj][0]=a0.x; wf[jj][1]=a0.y; wf[jj][2]=a0.z; wf[jj][3]=a0.w;
            wf[jj][4]=a1.x; wf[jj][5]=a1.y; wf[jj][6]=a1.z; wf[jj][7]=a1.w;
        }

        float u[BG_][4];
#pragma unroll
        for (int b = 0; b < BG_; ++b) {
            // explicit b128 broadcast reads (32-B aligned: b*384 + ci*32 bytes)
            const float4* xb4 = (const float4*)&x_lds[b][ci * DI_];
            const float4 xA = xb4[0], xB = xb4[1];
#pragma unroll
            for (int jj = 0; jj < 4; ++jj) {
                float s = wf[jj][0] * xA.x;
                s = fmaf(wf[jj][1], xA.y, s); s = fmaf(wf[jj][2], xA.z, s);
                s = fmaf(wf[jj][3], xA.w, s); s = fmaf(wf[jj][4], xB.x, s);
                s = fmaf(wf[jj][5], xB.y, s); s = fmaf(wf[jj][6], xB.z, s);
                s = fmaf(wf[jj][7], xB.w, s);
                u[b][jj] = s;
            }
            if (MODE >= 1) {
                float a = u[b][0]*vreg[b][0] + u[b][1]*vreg[b][1]
                        + u[b][2]*vreg[b][2] + u[b][3]*vreg[b][3];
                a += __shfl_xor(a, 1);
                a += __shfl_xor(a, 2);          // full 16-d dot within quad
                if (q == 0) e_lds[b][o] = __expf(a);
            } else {
                acc[b][0]+=u[b][0]; acc[b][1]+=u[b][1];
                acc[b][2]+=u[b][2]; acc[b][3]+=u[b][3];
            }
        }

        if (MODE >= 1) {
            __syncthreads();   // B: e_lds complete (also fences tile reads)
            {
                const int bb = t >> 5, l = t & 31;
                float s = e_lds[bb][l] + e_lds[bb][l + 32];
                s += __shfl_xor(s, 1);  s += __shfl_xor(s, 2);  s += __shfl_xor(s, 4);
                s += __shfl_xor(s, 8);  s += __shfl_xor(s, 16);
                if (l == 0) invS[bb] = 1.0f / s;
            }
            __syncthreads();   // C: invS ready
#pragma unroll
            for (int b = 0; b < BG_; ++b) {
                const float c = e_lds[b][o] * invS[b];
                acc[b][0] = fmaf(c, u[b][0], acc[b][0]);
                acc[b][1] = fmaf(c, u[b][1], acc[b][1]);
                acc[b][2] = fmaf(c, u[b][2], acc[b][2]);
                acc[b][3] = fmaf(c, u[b][3], acc[b][3]);
                if (MODE == 2 && q == 0)
                    rw[((size_t)(b0 + b) * NI_ + i) * NO_ + o] = c;
            }
        } else {
            __syncthreads();   // MODE 0: fence tile reads before next overwrite
        }

        ci = (ci + 1 == CI_) ? 0 : ci + 1;
    }

    // partial s: part[b][ch][4t..4t+3] (coalesced float4)
#pragma unroll
    for (int b = 0; b < BG_; ++b) {
        float4 val;
        val.x=acc[b][0]; val.y=acc[b][1]; val.z=acc[b][2]; val.w=acc[b][3];
        *((float4*)(part + (((size_t)(b0 + b) * CH_ + ch) * NOD_ + 4 * t))) = val;
    }
}

// Reduce partials over CH_ chunks (float4), squash over d, emit v.
// MODE 0: s*=1/64 -> v0 | MODE 1: w01 = v0 + squash(s1) | MODE 2: v2 -> d_out
template <int MODE>
__global__ __launch_bounds__(128)
void caps_squash(const float* __restrict__ part, const float* __restrict__ v0in,
                 float* __restrict__ vout)
{
    const int c4 = blockIdx.x * 128 + threadIdx.x;    // 0..16383: b*256 + o*4 + dq
    const int b = c4 >> 8, od4 = c4 & 255;
    const float4* p = (const float4*)part + (size_t)b * CH_ * 256 + od4;
    float4 s = {0.f, 0.f, 0.f, 0.f};
#pragma unroll 8
    for (int ch = 0; ch < CH_; ++ch) {
        float4 q = p[(size_t)ch * 256];
        s.x += q.x; s.y += q.y; s.z += q.z; s.w += q.w;
    }
    if (MODE == 0) { s.x*=(1.f/64.f); s.y*=(1.f/64.f); s.z*=(1.f/64.f); s.w*=(1.f/64.f); }
    float s2 = s.x*s.x + s.y*s.y + s.z*s.z + s.w*s.w;
    s2 += __shfl_xor(s2, 1); s2 += __shfl_xor(s2, 2);   // 4 dq-lanes = 16 d
    const float scale = s2 / ((1.0f + s2) * sqrtf(s2 + 1e-7f));
    float4 v; v.x = scale*s.x; v.y = scale*s.y; v.z = scale*s.z; v.w = scale*s.w;
    if (MODE == 1) {
        float4 v0 = ((const float4*)v0in)[c4];
        v.x += v0.x; v.y += v0.y; v.z += v0.z; v.w += v0.w;
    }
    ((float4*)vout)[c4] = v;
}

// Safety fallback (R11's passing kernel) — only if ws is unexpectedly tiny.
__global__ __launch_bounds__(1024, 1)
void caps_naive(const float* __restrict__ X, const float* __restrict__ W,
                float* __restrict__ outv, float* __restrict__ outc)
{
    __shared__ float xs[NI_ * DI_];
    __shared__ float agree[NO_];
    __shared__ float expo[NO_];
    __shared__ float s2sh[NO_];
    __shared__ float den;

    const int b = blockIdx.x, tid = threadIdx.x;
    const int o = tid >> 4, d = tid & 15;

    for (int f = tid; f < NI_ * DI_; f += 1024)
        xs[f] = X[(size_t)b * NI_ * DI_ + f];
    __syncthreads();

    float vprev = 0.f, v0 = 0.f, vout = 0.f;
    for (int phase = 0; phase < 3; ++phase) {
        float sacc = 0.f;
        for (int i = 0; i < NI_; ++i) {
            const float* wp = W + (size_t)i * 8192 + (size_t)tid * 8;
            const float* xp = xs + i * DI_;
            float u = 0.f;
#pragma unroll
            for (int k = 0; k < 8; ++k) u = fmaf(wp[k], xp[k], u);
            if (phase == 0) { sacc += u; continue; }
            if (d == 0) agree[o] = 0.f;
            __syncthreads();
            atomicAdd(&agree[o], u * vprev);
            __syncthreads();
            if (tid == 0) den = 0.f;
            __syncthreads();
            if (d == 0) { float e = __expf(agree[o]); expo[o] = e; atomicAdd(&den, e); }
            __syncthreads();
            float c = expo[o] / den;
            sacc = fmaf(c, u, sacc);
            if (phase == 2 && d == 0)
                outc[((size_t)b * NI_ + i) * NO_ + o] = c;
            __syncthreads();
        }
        if (phase == 0) sacc *= (1.0f / 64.0f);
        if (d == 0) s2sh[o] = 0.f;
        __syncthreads();
        atomicAdd(&s2sh[o], sacc * sacc);
        __syncthreads();
        const float s2 = s2sh[o];
        const float scale = s2 / ((1.0f + s2) * sqrtf(s2 + 1e-7f));
        const float vv = scale * sacc;
        if (phase == 0)      { v0 = vv; vprev = vv; }
        else if (phase == 1) { vprev = v0 + vv; }
        else                 { vout = vv; }
        __syncthreads();
    }
    outv[(size_t)b * (NO_ * DO_) + tid] = vout;
}

extern "C" void kernel_launch(void* const* d_in, const int* in_sizes, int n_in,
                              void* d_out, int out_size, void* d_ws, size_t ws_size,
                              hipStream_t stream)
{
    const float *X, *W;
    if (in_sizes[0] < in_sizes[1]) { X = (const float*)d_in[0]; W = (const float*)d_in[1]; }
    else                           { X = (const float*)d_in[1]; W = (const float*)d_in[0]; }

    float* out  = (float*)d_out;
    float* outv = out;             // v: [B,No,Do] fp32
    float* outc = out + V_ELEMS;   // c: [B,Ni,No] fp32

    const size_t needBig = ((size_t)B_ * CH_ * NOD_ + 2 * (size_t)B_ * NOD_) * sizeof(float);
    if (ws_size < needBig) {       // never expected (ws >= 64 MB measured R12)
        caps_naive<<<B_, 1024, 0, stream>>>(X, W, outv, outc);
        return;
    }

    float* part = (float*)d_ws;                      // 25.2 MB
    float* v0   = part + (size_t)B_ * CH_ * NOD_;
    float* w01  = v0 + (size_t)B_ * NOD_;

    dim3 gP(CH_, BSPLIT_), blk(256), gS(128), blkS(128);
    caps_pass<0><<<gP, blk, 0, stream>>>(X, W, nullptr, part, nullptr);
    caps_squash<0><<<gS, blkS, 0, stream>>>(part, nullptr, v0);
    caps_pass<1><<<gP, blk, 0, stream>>>(X, W, v0, part, nullptr);
    caps_squash<1><<<gS, blkS, 0, stream>>>(part, v0, w01);
    caps_pass<2><<<gP, blk, 0, stream>>>(X, W, w01, part, outc);
    caps_squash<2><<<gS, blkS, 0, stream>>>(part, nullptr, outv);
}

// Round 6
// 220.702 us; speedup vs baseline: 1.6156x; 1.0692x over previous
//
#include <hip/hip_runtime.h>

// CapsNet dynamic routing — fp32 in / fp32 out.
// Ladder: R0 66.3 -> R5 61.0 (phase rotation, +VALU 16.6->31%). R5's rotation
// (ch+3by)%12 broke by-sibling L2 sharing of W (FETCH 19.6->64 MB). Fix:
// co-resident blocks differ by 256 linear = dCh 64/-32 -> phase = ch%12 gives
// co-resident spread {0,4,8} AND keeps all 8 by-siblings (same ch) in the
// same phase -> W L2 reuse restored. Second change: x is BLOCK-UNIFORM data
// that was consuming 16 of 32 LDS ops/thread/ci as broadcast b128 reads ->
// move to the scalar pipe: s_load_dwordx8 x8 in one self-contained asm
// (loads + lgkmcnt(0) in a single block so the compiler's own lgkm
// accounting stays valid), issued AFTER the wf ds_reads so scalar latency
// overlaps LDS latency. x_lds deleted; FMAs become v_fma v,s,v (1 SGPR
// operand is architecturally free). VGPR ~80 (cap 170 at 3 waves/SIMD,
// no spill — R1/R4 lesson).
// B=64, Ni=1152, Di=8, No=64, Do=16.
// u[b,i,o,d] = sum_k W[i*8192 + (o*16+d)*8 + k] * x[b*9216 + i*8 + k]
// it0: c=1/64       -> s0 -> v0
// it1: l=<u,v0>     -> c1 -> s1 -> v1
// it2: l=<u,v0+v1>  -> c2 (OUT [B,Ni,No]) -> s2 -> v2 (OUT [B,No,Do])

#define B_      64
#define NI_     1152
#define DI_     8
#define NO_     64
#define DO_     16
#define NOD_    1024
#define CH_     96
#define CI_     12
#define BG_     8
#define BSPLIT_ 8
#define V_ELEMS 65536
#define PADR    33      // float4 slots per o-row in LDS tile (132 floats)
#define XBSTRIDE 36864  // NI_*DI_*4 bytes between consecutive b rows of X

static_assert(CH_ * CI_ == NI_, "chunking");
static_assert(BG_ * BSPLIT_ == B_, "b split");

typedef __attribute__((ext_vector_type(8))) float f8v;

// MODE 0: c=1/64 (applied in squash), acc sum_i u       -> part
// MODE 1: l=<u,v0>, softmax over o, acc c*u             -> part
// MODE 2: l=<u,v0+v1>, softmax, write c (fp32), acc c*u -> part
template <int MODE>
__global__ __launch_bounds__(256, 3)
void caps_pass(const float* __restrict__ X,
               const float* __restrict__ W,
               const float* __restrict__ vin,
               float* __restrict__ part,
               float* __restrict__ rw)
{
    __shared__ float4 wtile[NO_ * PADR];       // 33 KB padded W[i] tile
    __shared__ float  e_lds[BG_][NO_];         // 2 KB
    __shared__ float  invS[BG_];

    const int t  = threadIdx.x;
    const int o  = t >> 2, q = t & 3;
    const int ch = blockIdx.x;            // same-ch blocks 96 apart -> same XCD
    const int by = blockIdx.y;
    const int b0 = by * BG_;
    const int i0 = ch * CI_;

    // phase = ch%12: co-resident blocks (linear +-256 => ch +-64/32) get
    // phases {0,4,8} — de-lockstepped; by-siblings (same ch) stay in the
    // SAME phase so all 8 read the same W[i] simultaneously (L2 reuse).
    const int phase = ch % CI_;

    // routing vector -> registers: v[b][o*16 + q*4 + j]  (coalesced: addr = 4t)
    float vreg[BG_][4];
    if (MODE >= 1) {
#pragma unroll
        for (int b = 0; b < BG_; ++b) {
            float4 qv = *((const float4*)(vin + (size_t)(b0 + b) * NOD_ + 4 * t));
            vreg[b][0]=qv.x; vreg[b][1]=qv.y; vreg[b][2]=qv.z; vreg[b][3]=qv.w;
        }
    }

    float acc[BG_][4];
#pragma unroll
    for (int b = 0; b < BG_; ++b) { acc[b][0]=0.f; acc[b][1]=0.f; acc[b][2]=0.f; acc[b][3]=0.f; }

    const float4* Wq = (const float4*)W;

    int ci = phase;
    for (int cc = 0; cc < CI_; ++cc) {
        const int i = i0 + ci;

        // ---- stage W[i] (2048 float4 = 32 KB): 8 coalesced dwordx4/thread ----
        // Overwrite safety: all tile reads of the previous iteration precede
        // that iteration's barrier B/C (or MODE-0 end barrier).
        const float4* wg = Wq + (size_t)i * 2048;
        float4 tmp[8];
#pragma unroll
        for (int j = 0; j < 8; ++j) tmp[j] = wg[t + 256 * j];
#pragma unroll
        for (int j = 0; j < 8; ++j) {
            const int f = t + 256 * j;                    // linear float4 idx
            wtile[(f >> 5) * PADR + (f & 31)] = tmp[j];   // padded row
        }
        __syncthreads();   // A: tile ready

        // ---- wf = W[i][o][4q+jj][0..7] via 8 b128 reads (bank-optimal) ----
        // Issued BEFORE the x s_loads so LDS latency overlaps scalar latency.
        float wf[4][8];
#pragma unroll
        for (int jj = 0; jj < 4; ++jj) {
            float4 a0 = wtile[o * PADR + (4 * q + jj) * 2];
            float4 a1 = wtile[o * PADR + (4 * q + jj) * 2 + 1];
            wf[jj][0]=a0.x; wf[jj][1]=a0.y; wf[jj][2]=a0.z; wf[jj][3]=a0.w;
            wf[jj][4]=a1.x; wf[jj][5]=a1.y; wf[jj][6]=a1.z; wf[jj][7]=a1.w;
        }

        // ---- x[b0..b0+7][i][0..7] via scalar pipe: 8x s_load_dwordx8 ----
        // Block-uniform data; one self-contained asm (loads + wait) keeps the
        // compiler's lgkm accounting valid. lgkmcnt(0) also covers the wf
        // ds_reads above — their data is needed immediately after anyway.
        f8v xs0, xs1, xs2, xs3, xs4, xs5, xs6, xs7;
        {
            const float* xp  = X + ((size_t)b0 * NI_ + i) * DI_;
            const float* xp4 = xp + 4 * (size_t)NI_ * DI_;
            asm volatile(
                "s_load_dwordx8 %0, %8, 0\n\t"
                "s_load_dwordx8 %1, %8, 36864\n\t"
                "s_load_dwordx8 %2, %8, 73728\n\t"
                "s_load_dwordx8 %3, %8, 110592\n\t"
                "s_load_dwordx8 %4, %9, 0\n\t"
                "s_load_dwordx8 %5, %9, 36864\n\t"
                "s_load_dwordx8 %6, %9, 73728\n\t"
                "s_load_dwordx8 %7, %9, 110592\n\t"
                "s_waitcnt lgkmcnt(0)"
                : "=&s"(xs0), "=&s"(xs1), "=&s"(xs2), "=&s"(xs3),
                  "=&s"(xs4), "=&s"(xs5), "=&s"(xs6), "=&s"(xs7)
                : "s"(xp), "s"(xp4)
                : "memory");
        }

        float u[BG_][4];
#pragma unroll
        for (int b = 0; b < BG_; ++b) {
            const f8v xv = (b==0)?xs0:(b==1)?xs1:(b==2)?xs2:(b==3)?xs3
                         :(b==4)?xs4:(b==5)?xs5:(b==6)?xs6:xs7;   // folds at unroll
#pragma unroll
            for (int jj = 0; jj < 4; ++jj) {
                float s = wf[jj][0] * xv[0];
                s = fmaf(wf[jj][1], xv[1], s); s = fmaf(wf[jj][2], xv[2], s);
                s = fmaf(wf[jj][3], xv[3], s); s = fmaf(wf[jj][4], xv[4], s);
                s = fmaf(wf[jj][5], xv[5], s); s = fmaf(wf[jj][6], xv[6], s);
                s = fmaf(wf[jj][7], xv[7], s);
                u[b][jj] = s;
            }
            if (MODE >= 1) {
                float a = u[b][0]*vreg[b][0] + u[b][1]*vreg[b][1]
                        + u[b][2]*vreg[b][2] + u[b][3]*vreg[b][3];
                a += __shfl_xor(a, 1);
                a += __shfl_xor(a, 2);          // full 16-d dot within quad
                if (q == 0) e_lds[b][o] = __expf(a);
            } else {
                acc[b][0]+=u[b][0]; acc[b][1]+=u[b][1];
                acc[b][2]+=u[b][2]; acc[b][3]+=u[b][3];
            }
        }

        if (MODE >= 1) {
            __syncthreads();   // B: e_lds complete (also fences tile reads)
            {
                const int bb = t >> 5, l = t & 31;
                float s = e_lds[bb][l] + e_lds[bb][l + 32];
                s += __shfl_xor(s, 1);  s += __shfl_xor(s, 2);  s += __shfl_xor(s, 4);
                s += __shfl_xor(s, 8);  s += __shfl_xor(s, 16);
                if (l == 0) invS[bb] = 1.0f / s;
            }
            __syncthreads();   // C: invS ready
#pragma unroll
            for (int b = 0; b < BG_; ++b) {
                const float c = e_lds[b][o] * invS[b];
                acc[b][0] = fmaf(c, u[b][0], acc[b][0]);
                acc[b][1] = fmaf(c, u[b][1], acc[b][1]);
                acc[b][2] = fmaf(c, u[b][2], acc[b][2]);
                acc[b][3] = fmaf(c, u[b][3], acc[b][3]);
                if (MODE == 2 && q == 0)
                    rw[((size_t)(b0 + b) * NI_ + i) * NO_ + o] = c;
            }
        } else {
            __syncthreads();   // MODE 0: fence tile reads before next overwrite
        }

        ci = (ci + 1 == CI_) ? 0 : ci + 1;
    }

    // partial s: part[b][ch][4t..4t+3] (coalesced float4)
#pragma unroll
    for (int b = 0; b < BG_; ++b) {
        float4 val;
        val.x=acc[b][0]; val.y=acc[b][1]; val.z=acc[b][2]; val.w=acc[b][3];
        *((float4*)(part + (((size_t)(b0 + b) * CH_ + ch) * NOD_ + 4 * t))) = val;
    }
}

// Reduce partials over CH_ chunks (float4), squash over d, emit v.
// MODE 0: s*=1/64 -> v0 | MODE 1: w01 = v0 + squash(s1) | MODE 2: v2 -> d_out
template <int MODE>
__global__ __launch_bounds__(128)
void caps_squash(const float* __restrict__ part, const float* __restrict__ v0in,
                 float* __restrict__ vout)
{
    const int c4 = blockIdx.x * 128 + threadIdx.x;    // 0..16383: b*256 + o*4 + dq
    const int b = c4 >> 8, od4 = c4 & 255;
    const float4* p = (const float4*)part + (size_t)b * CH_ * 256 + od4;
    float4 s = {0.f, 0.f, 0.f, 0.f};
#pragma unroll 8
    for (int ch = 0; ch < CH_; ++ch) {
        float4 q = p[(size_t)ch * 256];
        s.x += q.x; s.y += q.y; s.z += q.z; s.w += q.w;
    }
    if (MODE == 0) { s.x*=(1.f/64.f); s.y*=(1.f/64.f); s.z*=(1.f/64.f); s.w*=(1.f/64.f); }
    float s2 = s.x*s.x + s.y*s.y + s.z*s.z + s.w*s.w;
    s2 += __shfl_xor(s2, 1); s2 += __shfl_xor(s2, 2);   // 4 dq-lanes = 16 d
    const float scale = s2 / ((1.0f + s2) * sqrtf(s2 + 1e-7f));
    float4 v; v.x = scale*s.x; v.y = scale*s.y; v.z = scale*s.z; v.w = scale*s.w;
    if (MODE == 1) {
        float4 v0 = ((const float4*)v0in)[c4];
        v.x += v0.x; v.y += v0.y; v.z += v0.z; v.w += v0.w;
    }
    ((float4*)vout)[c4] = v;
}

// Safety fallback (R11's passing kernel) — only if ws is unexpectedly tiny.
__global__ __launch_bounds__(1024, 1)
void caps_naive(const float* __restrict__ X, const float* __restrict__ W,
                float* __restrict__ outv, float* __restrict__ outc)
{
    __shared__ float xs[NI_ * DI_];
    __shared__ float agree[NO_];
    __shared__ float expo[NO_];
    __shared__ float s2sh[NO_];
    __shared__ float den;

    const int b = blockIdx.x, tid = threadIdx.x;
    const int o = tid >> 4, d = tid & 15;

    for (int f = tid; f < NI_ * DI_; f += 1024)
        xs[f] = X[(size_t)b * NI_ * DI_ + f];
    __syncthreads();

    float vprev = 0.f, v0 = 0.f, vout = 0.f;
    for (int phase = 0; phase < 3; ++phase) {
        float sacc = 0.f;
        for (int i = 0; i < NI_; ++i) {
            const float* wp = W + (size_t)i * 8192 + (size_t)tid * 8;
            const float* xp = xs + i * DI_;
            float u = 0.f;
#pragma unroll
            for (int k = 0; k < 8; ++k) u = fmaf(wp[k], xp[k], u);
            if (phase == 0) { sacc += u; continue; }
            if (d == 0) agree[o] = 0.f;
            __syncthreads();
            atomicAdd(&agree[o], u * vprev);
            __syncthreads();
            if (tid == 0) den = 0.f;
            __syncthreads();
            if (d == 0) { float e = __expf(agree[o]); expo[o] = e; atomicAdd(&den, e); }
            __syncthreads();
            float c = expo[o] / den;
            sacc = fmaf(c, u, sacc);
            if (phase == 2 && d == 0)
                outc[((size_t)b * NI_ + i) * NO_ + o] = c;
            __syncthreads();
        }
        if (phase == 0) sacc *= (1.0f / 64.0f);
        if (d == 0) s2sh[o] = 0.f;
        __syncthreads();
        atomicAdd(&s2sh[o], sacc * sacc);
        __syncthreads();
        const float s2 = s2sh[o];
        const float scale = s2 / ((1.0f + s2) * sqrtf(s2 + 1e-7f));
        const float vv = scale * sacc;
        if (phase == 0)      { v0 = vv; vprev = vv; }
        else if (phase == 1) { vprev = v0 + vv; }
        else                 { vout = vv; }
        __syncthreads();
    }
    outv[(size_t)b * (NO_ * DO_) + tid] = vout;
}

extern "C" void kernel_launch(void* const* d_in, const int* in_sizes, int n_in,
                              void* d_out, int out_size, void* d_ws, size_t ws_size,
                              hipStream_t stream)
{
    const float *X, *W;
    if (in_sizes[0] < in_sizes[1]) { X = (const float*)d_in[0]; W = (const float*)d_in[1]; }
    else                           { X = (const float*)d_in[1]; W = (const float*)d_in[0]; }

    float* out  = (float*)d_out;
    float* outv = out;             // v: [B,No,Do] fp32
    float* outc = out + V_ELEMS;   // c: [B,Ni,No] fp32

    const size_t needBig = ((size_t)B_ * CH_ * NOD_ + 2 * (size_t)B_ * NOD_) * sizeof(float);
    if (ws_size < needBig) {       // never expected (ws >= 64 MB measured R12)
        caps_naive<<<B_, 1024, 0, stream>>>(X, W, outv, outc);
        return;
    }

    float* part = (float*)d_ws;                      // 25.2 MB
    float* v0   = part + (size_t)B_ * CH_ * NOD_;
    float* w01  = v0 + (size_t)B_ * NOD_;

    dim3 gP(CH_, BSPLIT_), blk(256), gS(128), blkS(128);
    caps_pass<0><<<gP, blk, 0, stream>>>(X, W, nullptr, part, nullptr);
    caps_squash<0><<<gS, blkS, 0, stream>>>(part, nullptr, v0);
    caps_pass<1><<<gP, blk, 0, stream>>>(X, W, v0, part, nullptr);
    caps_squash<1><<<gS, blkS, 0, stream>>>(part, v0, w01);
    caps_pass<2><<<gP, blk, 0, stream>>>(X, W, w01, part, outc);
    caps_squash<2><<<gS, blkS, 0, stream>>>(part, nullptr, outv);
}